// Round 9
// baseline (87.352 us; speedup 1.0000x reference)
//
#include <hip/hip_runtime.h>
#include <stdint.h>

#define H_ 224
#define W_ 224
#define NPIX (H_ * W_)          // 50176
#define NQ4 (NPIX / 4)          // 12544 dwords per frame
#define ROWQ 56                 // dwords per row
#define NFRAMES 256
#define CHSTRIDE (8 * NPIX)     // 401408 floats between channels
#define GRAY_BYTES ((size_t)NFRAMES * NPIX)   // 12,845,056

__device__ __forceinline__ uint32_t udot4acc(uint32_t a, uint32_t b, uint32_t c) {
#if __has_builtin(__builtin_amdgcn_udot4)
    return __builtin_amdgcn_udot4(a, b, c, false);
#else
    c += (a & 0xffu) * (b & 0xffu);
    c += ((a >> 8) & 0xffu) * ((b >> 8) & 0xffu);
    c += ((a >> 16) & 0xffu) * ((b >> 16) & 0xffu);
    c += (a >> 24) * (b >> 24);
    return c;
#endif
}

__device__ __forceinline__ uint32_t quant1(float s) {
    float gr = s / 3.0f;
    float v = floorf(gr * 255.0f);
    v = fminf(fmaxf(v, 0.0f), 255.0f);
    return (uint32_t)(int)v;
}

// swizzled u8-packed histogram word index (bank near-uniform under random a)
__device__ __forceinline__ void hist_inc(uint32_t* hist, uint32_t a, uint32_t b) {
    uint32_t w = ((a << 6) | (b >> 2)) ^ (a & 31u);
    atomicAdd(&hist[w], 1u << ((b & 3u) << 3));
}

// ---------------- Kernel 1: pure streaming gray quantization ----------------
// 12544 blocks x 256 threads: full-BW streaming (proven round 1-3 pattern).
__global__ __launch_bounds__(256) void k_gray(const float* __restrict__ x,
                                              uint32_t* __restrict__ g) {
    int t = blockIdx.x * 256 + threadIdx.x;     // < 3,211,264 exact
    int q = t * 4;
    int b = q / CHSTRIDE;
    int rem = q - b * CHSTRIDE;
    const float4* p0 = reinterpret_cast<const float4*>(x + ((size_t)b * 3 + 0) * CHSTRIDE + rem);
    const float4* p1 = reinterpret_cast<const float4*>(x + ((size_t)b * 3 + 1) * CHSTRIDE + rem);
    const float4* p2 = reinterpret_cast<const float4*>(x + ((size_t)b * 3 + 2) * CHSTRIDE + rem);
    float4 a = *p0, bb = *p1, c = *p2;
    uint32_t v0 = quant1(a.x + bb.x + c.x);
    uint32_t v1 = quant1(a.y + bb.y + c.y);
    uint32_t v2 = quant1(a.z + bb.z + c.z);
    uint32_t v3 = quant1(a.w + bb.w + c.w);
    g[t] = v0 | (v1 << 8) | (v2 << 16) | (v3 << 24);
}

// ---- stats: con/dis/hom + sum(h^2) + cross sum(h_ij*h_ji); 512-thread version ----
__device__ __forceinline__ void stats_pass(const uint32_t* hist, int tid, int wave, int lane,
                                           double invnp, double inv2np2,
                                           double& conD, double& disD,
                                           double& homD, double& asmD) {
    uint32_t conU = 0, disU = 0, slinU = 0;
    float homF = 0.0f;
    #pragma unroll 4
    for (int itr = 0; itr < 32; ++itr) {
        int m = tid + (itr << 9);
        uint32_t w = hist[m];
        if (w) {                                   // empty rows skip (execz)
            int i = m >> 6;
            int b4 = (m & 63) ^ (i & 31);          // undo swizzle
            int d0 = i - (b4 << 2);
            slinU = udot4acc(w, w, slinU);
            #pragma unroll
            for (int k = 0; k < 4; ++k) {
                uint32_t bv = (w >> (k << 3)) & 0xffu;
                int d = d0 - k;
                uint32_t d2 = (uint32_t)(d * d);
                conU += bv * d2;
                disU += bv * (uint32_t)(d < 0 ? -d : d);
                homF += (float)bv * __builtin_amdgcn_rcpf(1.0f + (float)d2);
            }
        }
    }

    // cross term over 4x4 byte tiles; unit (it=lane, jt=(lane+s)&63), s = wave+8q
    uint32_t scrU = 0;
    #pragma unroll
    for (int q = 0; q < 8; ++q) {
        int s = wave + (q << 3);
        int jt = (lane + s) & 63;
        uint32_t A[4], Bw[4];
        #pragma unroll
        for (int k = 0; k < 4; ++k) {
            int ia = 4 * lane + k;
            A[k]  = hist[((ia << 6) | jt)   ^ (ia & 31)];
            int ib = 4 * jt + k;
            Bw[k] = hist[((ib << 6) | lane) ^ (ib & 31)];
        }
        if ((A[0] | A[1] | A[2] | A[3]) && (Bw[0] | Bw[1] | Bw[2] | Bw[3])) {
            uint32_t x0 = __builtin_amdgcn_perm(Bw[1], Bw[0], 0x05010400u);
            uint32_t x1 = __builtin_amdgcn_perm(Bw[1], Bw[0], 0x07030602u);
            uint32_t x2 = __builtin_amdgcn_perm(Bw[3], Bw[2], 0x05010400u);
            uint32_t x3 = __builtin_amdgcn_perm(Bw[3], Bw[2], 0x07030602u);
            uint32_t t0 = __builtin_amdgcn_perm(x2, x0, 0x05040100u);
            uint32_t t1 = __builtin_amdgcn_perm(x2, x0, 0x07060302u);
            uint32_t t2 = __builtin_amdgcn_perm(x3, x1, 0x05040100u);
            uint32_t t3 = __builtin_amdgcn_perm(x3, x1, 0x07060302u);
            scrU = udot4acc(A[0], t0, scrU);
            scrU = udot4acc(A[1], t1, scrU);
            scrU = udot4acc(A[2], t2, scrU);
            scrU = udot4acc(A[3], t3, scrU);
        }
    }

    conD += (double)conU * invnp;
    disD += (double)disU * invnp;
    homD += (double)homF * invnp;
    asmD += ((double)slinU + (double)scrU) * inv2np2;
}

// ---------------- Kernel 2: 2 offsets per block, 2 blocks/CU ----------------
// bid = (f/8)*16 + half*8 + (f%8): a frame's two blocks share an XCD (mod 8).
// half0: {(0,1) + fused std, (1,1)}   half1: {(1,0), (1,-1)}
__global__ __launch_bounds__(512, 4) void k_glcm(const uint32_t* __restrict__ gray,
                                                 double* __restrict__ part) {
    __shared__ uint32_t hist[16384];   // 64 KB u8 H[256][256], swizzled words
    __shared__ double red[64];

    const int bid = blockIdx.x;
    const int half = (bid >> 3) & 1;
    const int f = ((bid >> 4) << 3) | (bid & 7);
    const uint32_t* gf = gray + (size_t)f * NQ4;
    const int tid = threadIdx.x, lane = tid & 63, wave = tid >> 6;   // 8 waves

    uint4* h4 = reinterpret_cast<uint4*>(hist);
    const uint4 z4 = make_uint4(0u, 0u, 0u, 0u);
    double conD = 0.0, disD = 0.0, homD = 0.0, asmD = 0.0;
    uint32_t s1 = 0, s2 = 0;
    const double npA = 49952.0, npB = 49729.0;

    // ---- phase 1: (0,1) or (1,0), np = 49952 ----
    #pragma unroll
    for (int i = 0; i < 8; ++i) h4[tid + (i << 9)] = z4;
    __syncthreads();
    if (half == 0) {
        if (lane < 56) {
            for (int r = wave; r < H_; r += 8) {
                uint32_t A = gf[r * ROWQ + lane];
                s1 = udot4acc(A, 0x01010101u, s1);      // fused std sums
                s2 = udot4acc(A, A, s2);
                uint32_t An = __shfl_down(A, 1, 64);
                uint32_t Bv = (A >> 8) | (An << 24);    // cols 4l+1 .. 4l+4
                int cb = lane * 4;
                #pragma unroll
                for (int k = 0; k < 4; ++k) {
                    if (cb + k < W_ - 1)
                        hist_inc(hist, (A >> (8 * k)) & 0xffu, (Bv >> (8 * k)) & 0xffu);
                }
            }
        }
    } else {
        if (lane < 56) {
            for (int r = wave; r < H_ - 1; r += 8) {
                uint32_t A = gf[r * ROWQ + lane];
                uint32_t B = gf[(r + 1) * ROWQ + lane];
                #pragma unroll
                for (int k = 0; k < 4; ++k)
                    hist_inc(hist, (A >> (8 * k)) & 0xffu, (B >> (8 * k)) & 0xffu);
            }
        }
    }
    __syncthreads();
    stats_pass(hist, tid, wave, lane, 1.0 / npA, 1.0 / (2.0 * npA * npA),
               conD, disD, homD, asmD);
    __syncthreads();

    // ---- phase 2: (1,1) or (1,-1), np = 49729 ----
    #pragma unroll
    for (int i = 0; i < 8; ++i) h4[tid + (i << 9)] = z4;
    __syncthreads();
    if (half == 0) {
        if (lane < 56) {
            for (int r = wave; r < H_ - 1; r += 8) {
                uint32_t A = gf[r * ROWQ + lane];
                uint32_t B = gf[(r + 1) * ROWQ + lane];
                uint32_t Bn = __shfl_down(B, 1, 64);
                uint32_t Bv = (B >> 8) | (Bn << 24);    // cols 4l+1 .. 4l+4
                int cb = lane * 4;
                #pragma unroll
                for (int k = 0; k < 4; ++k) {
                    if (cb + k < W_ - 1)
                        hist_inc(hist, (A >> (8 * k)) & 0xffu, (Bv >> (8 * k)) & 0xffu);
                }
            }
        }
    } else {
        if (lane < 56) {
            for (int r = wave; r < H_ - 1; r += 8) {
                uint32_t A = gf[r * ROWQ + lane];
                uint32_t B = gf[(r + 1) * ROWQ + lane];
                uint32_t Bp = __shfl_up(B, 1, 64);
                uint32_t Bv = (B << 8) | (Bp >> 24);    // cols 4l-1 .. 4l+2
                int cb = lane * 4;
                #pragma unroll
                for (int k = 0; k < 4; ++k) {
                    if (cb + k >= 1)
                        hist_inc(hist, (A >> (8 * k)) & 0xffu, (Bv >> (8 * k)) & 0xffu);
                }
            }
        }
    }
    __syncthreads();
    stats_pass(hist, tid, wave, lane, 1.0 / npB, 1.0 / (2.0 * npB * npB),
               conD, disD, homD, asmD);

    // ---- reduce 6 doubles -> per-block partials ----
    double vals[6] = {(double)s1, (double)s2, conD, disD, homD, asmD};
    #pragma unroll
    for (int off = 32; off; off >>= 1) {
        #pragma unroll
        for (int i = 0; i < 6; ++i) vals[i] += __shfl_down(vals[i], off, 64);
    }
    if (lane == 0) {
        #pragma unroll
        for (int i = 0; i < 6; ++i) red[wave * 8 + i] = vals[i];
    }
    __syncthreads();
    if (tid == 0) {
        #pragma unroll
        for (int i = 0; i < 6; ++i) {
            double t = red[i];
            for (int w = 1; w < 8; ++w) t += red[w * 8 + i];
            part[(size_t)bid * 6 + i] = t;
        }
    }
}

// ---------------- Kernel 3: combine halves, finalize ----------------
__global__ __launch_bounds__(256) void k_final(const double* __restrict__ part,
                                               float* __restrict__ out) {
    int f = threadIdx.x;                          // 256 frames, 1 block
    int bid0 = ((f >> 3) << 4) + (f & 7);         // half0 block of frame f
    const double* p0 = part + (size_t)bid0 * 6;
    const double* p1 = p0 + 48;                   // half1 block = bid0 + 8
    double con = (p0[2] + p1[2]) * 0.25;
    double dis = (p0[3] + p1[3]) * 0.25;
    double hom = (p0[4] + p1[4]) * 0.25;
    double as  = (p0[5] + p1[5]) * 0.25;
    double N = (double)NPIX;
    double mean = p0[0] / N;
    double var = p0[1] / N - mean * mean;
    if (var < 0.0) var = 0.0;
    float* op = out + f * 6;
    op[0] = (float)sqrt(var);
    op[1] = (float)con;
    op[2] = (float)dis;
    op[3] = (float)hom;
    op[4] = (float)as;
    op[5] = (float)sqrt(as);
}

extern "C" void kernel_launch(void* const* d_in, const int* in_sizes, int n_in,
                              void* d_out, int out_size, void* d_ws, size_t ws_size,
                              hipStream_t stream) {
    const float* x = (const float*)d_in[0];
    float* out = (float*)d_out;
    uint32_t* gray = (uint32_t*)d_ws;                              // 12.8 MB
    double* part = (double*)((uint8_t*)d_ws + GRAY_BYTES);         // 512*6 doubles

    k_gray<<<NQ4, 256, 0, stream>>>(x, gray);                      // 12544 blocks
    k_glcm<<<NFRAMES * 2, 512, 0, stream>>>(gray, part);           // 512 blocks
    k_final<<<1, 256, 0, stream>>>(part, out);
}

// Round 10
// 74.016 us; speedup vs baseline: 1.1802x; 1.1802x over previous
//
#include <hip/hip_runtime.h>
#include <stdint.h>

#define H_ 224
#define W_ 224
#define NPIX (H_ * W_)          // 50176
#define NQ4 (NPIX / 4)          // 12544 dwords per frame
#define NFRAMES 256
#define NT 1024
#define NW 16
#define CROWS 8
#define NCHUNK (H_ / CROWS)     // 28
#define CPX (CROWS * W_)        // 1792 floats per channel per chunk
#define CQ4 (CPX / 4)           // 448 gray dwords per chunk
#define STGF (3 * CPX)          // 5376 floats per staging buffer
#define M10 (223 * 56)          // 12488: dwords with a valid row below

typedef __attribute__((address_space(1))) const uint32_t* gas_t;
typedef __attribute__((address_space(3))) uint32_t* las_t;

__device__ __forceinline__ void gload_lds16(const float* g, float* l) {
    __builtin_amdgcn_global_load_lds((gas_t)g, (las_t)l, 16, 0, 0);
}

__device__ __forceinline__ uint32_t udot4acc(uint32_t a, uint32_t b, uint32_t c) {
#if __has_builtin(__builtin_amdgcn_udot4)
    return __builtin_amdgcn_udot4(a, b, c, false);
#else
    c += (a & 0xffu) * (b & 0xffu);
    c += ((a >> 8) & 0xffu) * ((b >> 8) & 0xffu);
    c += ((a >> 16) & 0xffu) * ((b >> 16) & 0xffu);
    c += (a >> 24) * (b >> 24);
    return c;
#endif
}

__device__ __forceinline__ uint32_t quant1(float s) {
    float gr = s / 3.0f;
    float v = floorf(gr * 255.0f);
    v = fminf(fmaxf(v, 0.0f), 255.0f);
    return (uint32_t)(int)v;
}

// swizzled u8-packed histogram word index
__device__ __forceinline__ void hist_inc(uint32_t* hist, uint32_t a, uint32_t b) {
    uint32_t w = ((a << 6) | (b >> 2)) ^ (a & 31u);
    atomicAdd(&hist[w], 1u << ((b & 3u) << 3));
}

// ---- stats scan: con/dis via udot4 triple, hom per-k rcp, slin + cross ----
__device__ __forceinline__ void stats_scan(const uint32_t* hist, int tid, int wave, int lane,
                                           double invnp, double inv2np2,
                                           double& conD, double& disD,
                                           double& homD, double& asmD) {
    int conI = 0, disI = 0;
    uint32_t slinU = 0;
    float homF = 0.0f;
    #pragma unroll 4
    for (int itr = 0; itr < 16; ++itr) {
        int m = tid + (itr << 10);
        uint32_t w = hist[m];
        if (w) {                                   // empty word-groups skip (execz)
            int i = m >> 6;
            int c4 = (m & 63) ^ (i & 31);          // undo swizzle: col group
            int d0 = i - (c4 << 2);                // d for k=0
            slinU = udot4acc(w, w, slinU);
            int sb   = (int)udot4acc(w, 0x01010101u, 0u);
            int skb  = (int)udot4acc(w, 0x03020100u, 0u);
            int sk2b = (int)udot4acc(w, 0x09040100u, 0u);
            conI += d0 * d0 * sb - 2 * d0 * skb + sk2b;
            if (d0 == 1 || d0 == 2) {              // mixed-sign |d|: rare, exact path
                int t = 0;
                #pragma unroll
                for (int k = 0; k < 4; ++k) {
                    int d = d0 - k;
                    t += (int)((w >> (k << 3)) & 0xffu) * (d < 0 ? -d : d);
                }
                disI += t;
            } else {
                int t = d0 * sb - skb;             // uniform sign
                disI += (t < 0) ? -t : t;
            }
            #pragma unroll
            for (int k = 0; k < 4; ++k) {
                uint32_t bv = (w >> (k << 3)) & 0xffu;
                int d = d0 - k;
                homF += (float)bv * __builtin_amdgcn_rcpf(1.0f + (float)(d * d));
            }
        }
    }

    // cross term sum h_ij * h_ji over 4x4 byte tiles (unchanged, proven)
    uint32_t scrU = 0;
    #pragma unroll
    for (int q = 0; q < 4; ++q) {
        int s = wave + (q << 4);
        int jt = (lane + s) & 63;
        uint32_t A[4], Bw[4];
        #pragma unroll
        for (int k = 0; k < 4; ++k) {
            int ia = 4 * lane + k;
            A[k]  = hist[((ia << 6) | jt)   ^ (ia & 31)];
            int ib = 4 * jt + k;
            Bw[k] = hist[((ib << 6) | lane) ^ (ib & 31)];
        }
        if ((A[0] | A[1] | A[2] | A[3]) && (Bw[0] | Bw[1] | Bw[2] | Bw[3])) {
            uint32_t x0 = __builtin_amdgcn_perm(Bw[1], Bw[0], 0x05010400u);
            uint32_t x1 = __builtin_amdgcn_perm(Bw[1], Bw[0], 0x07030602u);
            uint32_t x2 = __builtin_amdgcn_perm(Bw[3], Bw[2], 0x05010400u);
            uint32_t x3 = __builtin_amdgcn_perm(Bw[3], Bw[2], 0x07030602u);
            uint32_t t0 = __builtin_amdgcn_perm(x2, x0, 0x05040100u);
            uint32_t t1 = __builtin_amdgcn_perm(x2, x0, 0x07060302u);
            uint32_t t2 = __builtin_amdgcn_perm(x3, x1, 0x05040100u);
            uint32_t t3 = __builtin_amdgcn_perm(x3, x1, 0x07060302u);
            scrU = udot4acc(A[0], t0, scrU);
            scrU = udot4acc(A[1], t1, scrU);
            scrU = udot4acc(A[2], t2, scrU);
            scrU = udot4acc(A[3], t3, scrU);
        }
    }

    conD += (double)conI * invnp;
    disD += (double)disI * invnp;
    homD += (double)homF * invnp;
    asmD += ((double)slinU + (double)scrU) * inv2np2;
}

// ---------------- fused kernel: one frame per block ----------------
__global__ __launch_bounds__(NT, 4) void k_fused(const float* __restrict__ x,
                                                 float* __restrict__ out) {
    __shared__ float stage[2][STGF];    // 43008 B DMA staging
    __shared__ uint32_t hist[16384];    // 65536 B u8 H[256][256], swizzled
    __shared__ uint32_t gsh[NQ4];       // 50176 B gray frame
    __shared__ double red[NW * 8];      // 1024 B

    const int f = blockIdx.x;
    const int bq = f >> 3, fq = f & 7;
    const int tid = threadIdx.x, lane = tid & 63, wave = tid >> 6;

    const float* xb = x + ((size_t)bq * 24 + fq) * NPIX;   // channel stride 8*NPIX
    float* stg = &stage[0][0];

    uint4* h4 = reinterpret_cast<uint4*>(hist);
    const uint4 z4 = make_uint4(0u, 0u, 0u, 0u);
    #pragma unroll
    for (int i = 0; i < 4; ++i) h4[tid + (i << 10)] = z4;

    // prologue: DMA chunk 0 -> stage[0]
    if (wave >= 9) {
        int base = (wave - 9) * 3;
        #pragma unroll
        for (int k = 0; k < 3; ++k) {
            int idx = base + k;
            int ch = idx / 7, blk = idx % 7;
            gload_lds16(xb + (size_t)ch * (8 * NPIX) + blk * 256 + lane * 4,
                        stg + ch * CPX + blk * 256);
        }
    }
    __syncthreads();   // full drain once: chunk 0 staged, hist zeroed

    // ---- stream: counted-vmcnt pipeline; quant + std + (0,1) atomics ----
    uint32_t s1 = 0, s2 = 0;
    for (int c = 0; c < NCHUNK; ++c) {
        const int bs = c & 1;
        if (wave >= 9) {
            if (c + 1 < NCHUNK) {
                int base = (wave - 9) * 3;
                #pragma unroll
                for (int k = 0; k < 3; ++k) {
                    int idx = base + k;
                    int ch = idx / 7, blk = idx % 7;
                    gload_lds16(xb + (size_t)ch * (8 * NPIX) + (size_t)(c + 1) * CPX + blk * 256 + lane * 4,
                                stg + (bs ^ 1) * STGF + ch * CPX + blk * 256);
                }
                asm volatile("s_waitcnt vmcnt(3)" ::: "memory");  // chunk c landed; c+1 in flight
            } else {
                asm volatile("s_waitcnt vmcnt(0)" ::: "memory");  // final chunk landed
            }
            __builtin_amdgcn_sched_barrier(0);
        }
        __builtin_amdgcn_s_barrier();          // stage[bs] valid for all waves
        __builtin_amdgcn_sched_barrier(0);
        if (tid < CQ4) {                       // waves 0..6 process chunk c
            const float* st = stg + bs * STGF;
            float4 av = *reinterpret_cast<const float4*>(st + 0 * CPX + 4 * tid);
            float4 bv = *reinterpret_cast<const float4*>(st + 1 * CPX + 4 * tid);
            float4 cv = *reinterpret_cast<const float4*>(st + 2 * CPX + 4 * tid);
            uint32_t v0 = quant1(av.x + bv.x + cv.x);
            uint32_t v1 = quant1(av.y + bv.y + cv.y);
            uint32_t v2 = quant1(av.z + bv.z + cv.z);
            uint32_t v3 = quant1(av.w + bv.w + cv.w);
            uint32_t pk = v0 | (v1 << 8) | (v2 << 16) | (v3 << 24);
            gsh[c * CQ4 + tid] = pk;
            s1 += v0 + v1 + v2 + v3;
            s2 += v0 * v0 + v1 * v1 + v2 * v2 + v3 * v3;
            uint32_t nx = __shfl_down(pk, 1, 64);
            #pragma unroll
            for (int k = 0; k < 3; ++k) {      // in-dword (0,1) pairs: always valid
                hist_inc(hist, (pk >> (8 * k)) & 0xffu, (pk >> (8 * k + 8)) & 0xffu);
            }
            int m56 = tid % 56;                // c*448 == 0 mod 56
            if (lane != 63 && m56 != 55) {     // cross-dword pair
                hist_inc(hist, pk >> 24, nx & 0xffu);
            }
        }
        __builtin_amdgcn_s_barrier();          // stage[bs] free before next issue
    }
    __syncthreads();                           // full drain: gsh + atomics visible

    // deferred lane-63 cross-dword (0,1) pairs
    if (tid < 196) {
        int m = tid * 64 + 63;
        if (m % 56 != 55) hist_inc(hist, gsh[m] >> 24, gsh[m + 1] & 0xffu);
    }
    __syncthreads();

    double conD = 0.0, disD = 0.0, homD = 0.0, asmD = 0.0;
    const double npA = 49952.0, npB = 49729.0;
    const double invA = 1.0 / npA, invB = 1.0 / npB;
    const double invA2 = 1.0 / (2.0 * npA * npA), invB2 = 1.0 / (2.0 * npB * npB);

    stats_scan(hist, tid, wave, lane, invA, invA2, conD, disD, homD, asmD);   // (0,1)
    __syncthreads();

    // ---- offset (1,1): flat all-lane sweep ----
    #pragma unroll
    for (int i = 0; i < 4; ++i) h4[tid + (i << 10)] = z4;
    __syncthreads();
    #pragma unroll 2
    for (int it = 0; it < 13; ++it) {
        int m = tid + (it << 10);
        int mc = (m < M10) ? m : (M10 - 1);    // clamp keeps shfl sources exact
        uint32_t A = gsh[mc];
        uint32_t B = gsh[mc + 56];
        uint32_t Bn = __shfl_down(B, 1, 64);
        uint32_t Bv = (B >> 8) | (Bn << 24);
        if (m < M10) {
            hist_inc(hist, A & 0xffu, Bv & 0xffu);
            hist_inc(hist, (A >> 8) & 0xffu, (Bv >> 8) & 0xffu);
            hist_inc(hist, (A >> 16) & 0xffu, (Bv >> 16) & 0xffu);
            if (lane != 63 && m % 56 != 55)
                hist_inc(hist, A >> 24, Bv >> 24);
        }
    }
    if (tid < 195) {                           // lane-63 boundary fixup
        int m = tid * 64 + 63;
        if (m < M10 && m % 56 != 55)
            hist_inc(hist, gsh[m] >> 24, gsh[m + 57] & 0xffu);
    }
    __syncthreads();
    stats_scan(hist, tid, wave, lane, invB, invB2, conD, disD, homD, asmD);
    __syncthreads();

    // ---- offset (1,0): flat all-lane sweep, no shfl ----
    #pragma unroll
    for (int i = 0; i < 4; ++i) h4[tid + (i << 10)] = z4;
    __syncthreads();
    #pragma unroll 2
    for (int it = 0; it < 13; ++it) {
        int m = tid + (it << 10);
        if (m < M10) {
            uint32_t A = gsh[m];
            uint32_t B = gsh[m + 56];
            #pragma unroll
            for (int k = 0; k < 4; ++k)
                hist_inc(hist, (A >> (8 * k)) & 0xffu, (B >> (8 * k)) & 0xffu);
        }
    }
    __syncthreads();
    stats_scan(hist, tid, wave, lane, invA, invA2, conD, disD, homD, asmD);
    __syncthreads();

    // ---- offset (1,-1): flat all-lane sweep ----
    #pragma unroll
    for (int i = 0; i < 4; ++i) h4[tid + (i << 10)] = z4;
    __syncthreads();
    #pragma unroll 2
    for (int it = 0; it < 13; ++it) {
        int m = tid + (it << 10);
        int mc = (m < M10) ? m : (M10 - 1);
        uint32_t A = gsh[mc];
        uint32_t B = gsh[mc + 56];
        uint32_t Bp = __shfl_up(B, 1, 64);
        uint32_t Bv = (B << 8) | (Bp >> 24);
        if (m < M10) {
            if (lane != 0 && m % 56 != 0)
                hist_inc(hist, A & 0xffu, Bv & 0xffu);
            hist_inc(hist, (A >> 8) & 0xffu, (Bv >> 8) & 0xffu);
            hist_inc(hist, (A >> 16) & 0xffu, (Bv >> 16) & 0xffu);
            hist_inc(hist, A >> 24, Bv >> 24);
        }
    }
    if (tid >= 1 && tid < 196) {               // lane-0 boundary fixup
        int m = tid * 64;
        if (m < M10 && m % 56 != 0)
            hist_inc(hist, gsh[m] & 0xffu, gsh[m + 55] >> 24);
    }
    __syncthreads();
    stats_scan(hist, tid, wave, lane, invB, invB2, conD, disD, homD, asmD);

    // ---- fused reduction of 6 doubles, finalize ----
    double vals[6] = {(double)s1, (double)s2, conD, disD, homD, asmD};
    #pragma unroll
    for (int off = 32; off; off >>= 1) {
        #pragma unroll
        for (int i = 0; i < 6; ++i) vals[i] += __shfl_down(vals[i], off, 64);
    }
    if (lane == 0) {
        #pragma unroll
        for (int i = 0; i < 6; ++i) red[wave * 8 + i] = vals[i];
    }
    __syncthreads();
    if (tid == 0) {
        double acc[6];
        #pragma unroll
        for (int i = 0; i < 6; ++i) {
            double t = red[i];
            for (int w = 1; w < NW; ++w) t += red[w * 8 + i];
            acc[i] = t;
        }
        double N = (double)NPIX;
        double mean = acc[0] / N;
        double var = acc[1] / N - mean * mean;
        if (var < 0.0) var = 0.0;
        float* op = out + f * 6;
        op[0] = (float)sqrt(var);
        op[1] = (float)(acc[2] * 0.25);
        op[2] = (float)(acc[3] * 0.25);
        op[3] = (float)(acc[4] * 0.25);
        op[4] = (float)(acc[5] * 0.25);
        op[5] = (float)sqrt(acc[5] * 0.25);
    }
}

extern "C" void kernel_launch(void* const* d_in, const int* in_sizes, int n_in,
                              void* d_out, int out_size, void* d_ws, size_t ws_size,
                              hipStream_t stream) {
    const float* x = (const float*)d_in[0];
    float* out = (float*)d_out;
    k_fused<<<NFRAMES, NT, 0, stream>>>(x, out);
}